// Round 8
// baseline (294.320 us; speedup 1.0000x reference)
//
#include <hip/hip_runtime.h>
#include <hip/hip_bf16.h>

typedef float  f32x4  __attribute__((ext_vector_type(4)));
typedef __bf16 bf16x4 __attribute__((ext_vector_type(4)));
typedef __bf16 bf16x8 __attribute__((ext_vector_type(8)));

#define B_SZ  64
#define NTOK  341
#define DM    768
#define NH    12
#define HD    64
#define MTOT  (B_SZ*NTOK)  // 21824
#define MP    21888        // 171*128
#define EQKV  2304

#define EXP2F(x) __builtin_amdgcn_exp2f(x)

__device__ __forceinline__ void gload_lds16(const __bf16* g, void* l) {
    __builtin_amdgcn_global_load_lds(
        (const __attribute__((address_space(1))) void*)g,
        (__attribute__((address_space(3))) void*)l, 16, 0, 0);
}

// ---------------- fp32 -> bf16 convert ----------------
__global__ void cvt_kernel(const float* __restrict__ in, __bf16* __restrict__ out, int n4) {
    int i = blockIdx.x * blockDim.x + threadIdx.x;
    const int stride = gridDim.x * blockDim.x;
    for (; i < n4; i += stride) {
        const float4 f = ((const float4*)in)[i];
        bf16x4 v;
        v[0] = (__bf16)f.x; v[1] = (__bf16)f.y; v[2] = (__bf16)f.z; v[3] = (__bf16)f.w;
        ((bf16x4*)out)[i] = v;
    }
}

// ---------------- 128x128xBK64 GEMM, XCD-chunked grid + 2-phase prefetch ----------------
// 1-D grid, NT = n-tiles. m204 bijective XCD map; within an XCD chunk wg runs
// n-fastest => consecutive blocks share the A-panel (L2-resident); W is L2-resident.
template <int EPI, int EN, int NT>   // EN = output row-stride
__global__ __launch_bounds__(256) void gemm128(
    const __bf16* __restrict__ A, const __bf16* __restrict__ Bw,
    const float* __restrict__ bias,
    __bf16* __restrict__ obf, float* __restrict__ of32)
{
    __shared__ __bf16 As[2][128 * 64];   // 2 x 16 KiB
    __shared__ __bf16 Bs[2][128 * 64];

    const int tid  = threadIdx.x;
    const int lane = tid & 63;
    const int w    = tid >> 6;
    const int wm   = w >> 1, wn = w & 1;
    const int qi   = lane & 15;
    const int g    = lane >> 4;

    const int nwg = gridDim.x;
    const int bid = blockIdx.x;
    const int qq = nwg >> 3, rr = nwg & 7;
    const int xcd = bid & 7, idx = bid >> 3;
    const int wg = (xcd < rr ? xcd * (qq + 1) : rr * (qq + 1) + (xcd - rr) * qq) + idx;
    const int mtile = wg / NT;
    const int ntile = wg % NT;
    const long a_row0 = (long)mtile * 128;
    const long n0     = (long)ntile * 128;

    const int slot = lane & 7;
    const __bf16* aP[4];
    const __bf16* bP[4];
#pragma unroll
    for (int it = 0; it < 4; ++it) {
        const int lrow = it * 32 + w * 8 + (lane >> 3);
        const int scol = (slot ^ (lrow & 7)) * 8;
        aP[it] = A + (a_row0 + lrow) * DM + scol;
        const int gcol = (lrow & 64) | ((lrow & 15) << 2) | ((lrow >> 4) & 3);
        bP[it] = Bw + (n0 + gcol) * DM + scol;
    }

    const f32x4 fzero = {0.f, 0.f, 0.f, 0.f};
    f32x4 acc[4][4];
#pragma unroll
    for (int i = 0; i < 4; ++i)
#pragma unroll
        for (int j = 0; j < 4; ++j) acc[i][j] = fzero;

#define STAGE(P, K0) do { \
    _Pragma("unroll") for (int it = 0; it < 4; ++it) { \
        gload_lds16(aP[it] + (K0), (char*)(&As[P][0]) + it * 4096 + w * 1024); \
        gload_lds16(bP[it] + (K0), (char*)(&Bs[P][0]) + it * 4096 + w * 1024); \
    } } while (0)

    STAGE(0, 0);
    __syncthreads();            // vmcnt(0) drain + barrier (tile 0 ready)

    int cur = 0;
    for (int k0 = 0; k0 < DM; k0 += 64) {
        if (k0 + 64 < DM) STAGE(cur ^ 1, k0 + 64);   // prefetch next tile (in flight under MFMA)

        const __bf16* pA = &As[cur][0];
        const __bf16* pB = &Bs[cur][0];
        bf16x8 af[4][2], bfr[4][2];
#pragma unroll
        for (int i = 0; i < 4; ++i) {
            const int fr = wm * 64 + i * 16 + qi;
#pragma unroll
            for (int ks = 0; ks < 2; ++ks)
                af[i][ks] = *(const bf16x8*)(pA + fr * 64 + (((ks << 2) + g) ^ (fr & 7)) * 8);
        }
#pragma unroll
        for (int j = 0; j < 4; ++j) {
            const int frb = wn * 64 + j * 16 + qi;
#pragma unroll
            for (int ks = 0; ks < 2; ++ks)
                bfr[j][ks] = *(const bf16x8*)(pB + frb * 64 + (((ks << 2) + g) ^ (frb & 7)) * 8);
        }
#pragma unroll
        for (int ks = 0; ks < 2; ++ks)
#pragma unroll
            for (int j = 0; j < 4; ++j)
#pragma unroll
                for (int i = 0; i < 4; ++i)
                    acc[i][j] = __builtin_amdgcn_mfma_f32_16x16x32_bf16(
                        af[i][ks], bfr[j][ks], acc[i][j], 0, 0, 0);

        __syncthreads();        // drains prefetch vmcnt(0) + separates read/write of buffers
        cur ^= 1;
    }
#undef STAGE

    const long ge0 = n0 + wn * 64 + qi * 4;
    const float4 b4 = *(const float4*)(bias + ge0);
    // q-scale folds hd^-0.5 AND log2(e) so attention can use exp2 directly
    const float mul = (EPI == 0 && (n0 + wn * 64) < DM) ? 0.125f * 1.44269504f : 1.f;
#pragma unroll
    for (int i = 0; i < 4; ++i) {
#pragma unroll
        for (int r = 0; r < 4; ++r) {
            const long m = a_row0 + wm * 64 + i * 16 + g * 4 + r;
            if (m < MTOT) {
                if (EPI == 0) {
                    bf16x4 pv;
                    pv[0] = (__bf16)((acc[i][0][r] + b4.x) * mul);
                    pv[1] = (__bf16)((acc[i][1][r] + b4.y) * mul);
                    pv[2] = (__bf16)((acc[i][2][r] + b4.z) * mul);
                    pv[3] = (__bf16)((acc[i][3][r] + b4.w) * mul);
                    *(bf16x4*)(obf + m * EN + ge0) = pv;
                } else {
                    float4 o;
                    o.x = acc[i][0][r] + b4.x;
                    o.y = acc[i][1][r] + b4.y;
                    o.z = acc[i][2][r] + b4.z;
                    o.w = acc[i][3][r] + b4.w;
                    *(float4*)(of32 + m * EN + ge0) = o;
                }
            }
        }
    }
}

// ---------------- attention ----------------
// qkv layout: [M=21824, 2304]; q = cols 0..767 (pre-scaled by 0.125*log2e), k = +768, v = +1536.
// One block per (b,h); 16 waves. K staged in LDS (row-major, XOR-swizzled, via global_load_lds);
// V staged in LDS in MFMA-fragment order (double-XOR swizzle). Rows >= 341 of K hold clamped
// duplicate data — every consumer masks k >= 341 before use.
template <bool FULLK, bool MASKALL>
__device__ __forceinline__ void attn_group(
    const __bf16* __restrict__ qkv, const __bf16* kL, const char* vL,
    __bf16* __restrict__ ao, long rowb, int h, int q0, int qi, int g)
{
    constexpr int NKF = FULLK ? 22 : 6;
    constexpr int NJ  = FULLK ? 11 : 3;

    int qrow = q0 + qi; if (qrow > NTOK - 1) qrow = NTOK - 1;
    const __bf16* qsrc = qkv + (rowb + qrow) * EQKV + h * HD + g * 8;
    const bf16x8 qf0 = *(const bf16x8*)(qsrc);
    const bf16x8 qf1 = *(const bf16x8*)(qsrc + 32);

    const f32x4 fzero = {0.f, 0.f, 0.f, 0.f};
    f32x4 st[NKF];
#pragma unroll
    for (int kf = 0; kf < NKF; ++kf) {
        const int krow = kf * 16 + qi;
        const __bf16* kbase = kL + krow * 64;
        const bf16x8 k0v = *(const bf16x8*)(kbase + ((g       ^ (krow & 7)) << 3));
        const bf16x8 k1v = *(const bf16x8*)(kbase + (((4 + g) ^ (krow & 7)) << 3));
        f32x4 a = fzero;
        a = __builtin_amdgcn_mfma_f32_16x16x32_bf16(k0v, qf0, a, 0, 0, 0);
        a = __builtin_amdgcn_mfma_f32_16x16x32_bf16(k1v, qf1, a, 0, 0, 0);
        st[kf] = a;
    }

    const int qg = q0 + qi;
    float sum = 0.f;
    if (MASKALL) {
        int limit;
        if (qg == 0)       limit = NTOK;
        else if (qg < 5)   limit = 5;
        else if (qg < 21)  limit = 21;
        else if (qg < 85)  limit = 85;
        else               limit = NTOK;
#pragma unroll
        for (int kf = 0; kf < NKF; ++kf)
#pragma unroll
            for (int r = 0; r < 4; ++r) {
                const int k = kf * 16 + g * 4 + r;
                const float p = (k < limit) ? EXP2F(st[kf][r]) : 0.f;
                st[kf][r] = p; sum += p;
            }
    } else {
#pragma unroll
        for (int kf = 0; kf < NKF - 1; ++kf)
#pragma unroll
            for (int r = 0; r < 4; ++r) {
                const float p = EXP2F(st[kf][r]);
                st[kf][r] = p; sum += p;
            }
#pragma unroll
        for (int r = 0; r < 4; ++r) {   // kf = 21 tail: k = 336 + g*4 + r < 341
            const float p = (g * 4 + r < 5) ? EXP2F(st[NKF - 1][r]) : 0.f;
            st[NKF - 1][r] = p; sum += p;
        }
    }
    sum += __shfl_xor(sum, 16);
    sum += __shfl_xor(sum, 32);
    const float rinv = 1.f / sum;

    f32x4 oacc[4];
#pragma unroll
    for (int db = 0; db < 4; ++db) oacc[db] = fzero;

#pragma unroll
    for (int j = 0; j < NJ; ++j) {
        bf16x8 pf;
#pragma unroll
        for (int r = 0; r < 4; ++r) {
            pf[r]     = (__bf16)st[2 * j][r];
            pf[4 + r] = (__bf16)st[2 * j + 1][r];
        }
#pragma unroll
        for (int db = 0; db < 4; ++db) {
            const int d  = db * 16 + qi;
            const int xd = (qi & 7) ^ ((2 * db + (qi >> 3)) & 7);
            const int sp = (4 * j + g) ^ xd;
            const bf16x8 vf = *(const bf16x8*)(vL + d * 768 + sp * 16);
            oacc[db] = __builtin_amdgcn_mfma_f32_16x16x32_bf16(vf, pf, oacc[db], 0, 0, 0);
        }
    }

    if (qg < NTOK) {
        const long orow = (rowb + qg) * DM + h * HD;
#pragma unroll
        for (int db = 0; db < 4; ++db) {
            bf16x4 pv;
#pragma unroll
            for (int r = 0; r < 4; ++r) pv[r] = (__bf16)(oacc[db][r] * rinv);
            *(bf16x4*)(ao + orow + db * 16 + g * 4) = pv;
        }
    }
}

__global__ __launch_bounds__(1024) void attn_kernel(
    const __bf16* __restrict__ qkv, __bf16* __restrict__ ao)
{
    const int h = blockIdx.x;   // 0..11
    const int b = blockIdx.y;   // 0..63
    const long rowb = (long)b * NTOK;

    __shared__ __bf16 kL[352 * 64];   // 45056 B, row-major K with XOR slot swizzle
    __shared__ char   vL[64 * 768];   // 49152 B, V^T fragment-order

    const int tid  = threadIdx.x;
    const int lane = tid & 63;
    const int w    = tid >> 6;   // 0..15

    // stage K via global_load_lds: linear LDS dest, inverse-swizzled global source.
    // piece c (< 2816): row = c>>3, slot j = c&7; LDS slot j holds source column j^(row&7).
#pragma unroll
    for (int it = 0; it < 3; ++it) {
        const int c = it * 1024 + tid;
        if (c < 2816) {
            const int row = c >> 3;
            const int j   = c & 7;
            const int srcrow = (row < NTOK) ? row : (NTOK - 1);   // stay in-bounds; masked later
            const __bf16* src = qkv + (rowb + srcrow) * EQKV + DM + h * HD + ((j ^ (row & 7)) << 3);
            gload_lds16(src, (char*)kL + it * 16384 + w * 1024);
        }
    }

    // stage V (transposed, double-XOR swizzle)
#pragma unroll
    for (int it = 0; it < 3; ++it) {
        const int c = it * 1024 + tid;
        if (c < 2816) {
            const int n  = c >> 3;
            const int dc = (c & 7) << 3;
            bf16x8 e;
            if (n < NTOK) e = *(const bf16x8*)(qkv + (rowb + n) * EQKV + 1536 + h * HD + dc);
            else { e[0]=e[1]=e[2]=e[3]=e[4]=e[5]=e[6]=e[7] = (__bf16)0.f; }
            const int s   = ((n >> 5) << 2) | ((n >> 2) & 3);     // 4j+g
            const int off = (((n >> 4) & 1) << 3) | ((n & 3) << 1);
            const int x   = c & 7;                                 // (d>>3)&7
#pragma unroll
            for (int i = 0; i < 8; ++i) {
                const int sp = s ^ i ^ x;                          // i == d&7
                *(__bf16*)(vL + (dc + i) * 768 + sp * 16 + off) = e[i];
            }
        }
    }
    __syncthreads();

    const int g  = lane >> 4;
    const int qi = lane & 15;

    // 16 waves cover 22 q-groups: gi = w and w+16
    for (int gi = w; gi < 22; gi += 16) {
        const int q0 = gi * 16;
        if (gi == 0 || gi == 5)
            attn_group<true,  true >(qkv, kL, vL, ao, rowb, h, q0, qi, g);
        else if (gi < 5)
            attn_group<false, true >(qkv, kL, vL, ao, rowb, h, q0, qi, g);
        else
            attn_group<true,  false>(qkv, kL, vL, ao, rowb, h, q0, qi, g);
    }
}

extern "C" void kernel_launch(void* const* d_in, const int* in_sizes, int n_in,
                              void* d_out, int out_size, void* d_ws, size_t ws_size,
                              hipStream_t stream) {
    const float* x      = (const float*)d_in[0];
    const float* qkv_w  = (const float*)d_in[1];
    const float* qkv_b  = (const float*)d_in[2];
    const float* proj_w = (const float*)d_in[3];
    const float* proj_b = (const float*)d_in[4];
    float* out = (float*)d_out;

    char* ws = (char*)d_ws;
    constexpr size_t XB_BYTES  = (size_t)MP * DM * 2;
    constexpr size_t WQ_OFF    = XB_BYTES;
    constexpr size_t WP_OFF    = WQ_OFF + (size_t)EQKV * DM * 2;
    constexpr size_t QKV_OFF   = WP_OFF + (size_t)DM * DM * 2;

    __bf16* xb  = (__bf16*)(ws);           // x bf16 [MP,768]; reused as attn-out
    __bf16* wq  = (__bf16*)(ws + WQ_OFF);
    __bf16* wp  = (__bf16*)(ws + WP_OFF);
    __bf16* qkv = (__bf16*)(ws + QKV_OFF); // [MTOT, 2304] bf16

    cvt_kernel<<<2048, 256, 0, stream>>>(x,      xb, MTOT * DM / 4);
    cvt_kernel<<<1728, 256, 0, stream>>>(qkv_w,  wq, EQKV * DM / 4);
    cvt_kernel<<<576,  256, 0, stream>>>(proj_w, wp, DM * DM / 4);

    gemm128<0, EQKV, 18><<<171 * 18, 256, 0, stream>>>(xb, wq, qkv_b, qkv, nullptr);
    attn_kernel<<<dim3(NH, B_SZ), 1024, 0, stream>>>(qkv, xb);
    gemm128<1, DM, 6><<<171 * 6, 256, 0, stream>>>(xb, wp, proj_b, nullptr, out);
}

// Round 9
// 267.406 us; speedup vs baseline: 1.1006x; 1.1006x over previous
//
#include <hip/hip_runtime.h>
#include <hip/hip_bf16.h>

typedef float  f32x4  __attribute__((ext_vector_type(4)));
typedef __bf16 bf16x4 __attribute__((ext_vector_type(4)));
typedef __bf16 bf16x8 __attribute__((ext_vector_type(8)));

#define B_SZ  64
#define NTOK  341
#define DM    768
#define NH    12
#define HD    64
#define MTOT  (B_SZ*NTOK)  // 21824
#define MP    21888        // 171*128
#define EQKV  2304

#define EXP2F(x) __builtin_amdgcn_exp2f(x)

__device__ __forceinline__ void gload_lds16(const __bf16* g, void* l) {
    __builtin_amdgcn_global_load_lds(
        (const __attribute__((address_space(1))) void*)g,
        (__attribute__((address_space(3))) void*)l, 16, 0, 0);
}

// ---------------- fp32 -> bf16 convert ----------------
__global__ void cvt_kernel(const float* __restrict__ in, __bf16* __restrict__ out, int n4) {
    int i = blockIdx.x * blockDim.x + threadIdx.x;
    const int stride = gridDim.x * blockDim.x;
    for (; i < n4; i += stride) {
        const float4 f = ((const float4*)in)[i];
        bf16x4 v;
        v[0] = (__bf16)f.x; v[1] = (__bf16)f.y; v[2] = (__bf16)f.z; v[3] = (__bf16)f.w;
        ((bf16x4*)out)[i] = v;
    }
}

// ---------------- 128x128xBK64 GEMM, XCD-chunked grid + 2-phase prefetch ----------------
template <int EPI, int EN, int NT>   // EN = output row-stride
__global__ __launch_bounds__(256) void gemm128(
    const __bf16* __restrict__ A, const __bf16* __restrict__ Bw,
    const float* __restrict__ bias,
    __bf16* __restrict__ obf, float* __restrict__ of32)
{
    __shared__ __bf16 As[2][128 * 64];
    __shared__ __bf16 Bs[2][128 * 64];

    const int tid  = threadIdx.x;
    const int lane = tid & 63;
    const int w    = tid >> 6;
    const int wm   = w >> 1, wn = w & 1;
    const int qi   = lane & 15;
    const int g    = lane >> 4;

    const int nwg = gridDim.x;
    const int bid = blockIdx.x;
    const int qq = nwg >> 3, rr = nwg & 7;
    const int xcd = bid & 7, idx = bid >> 3;
    const int wg = (xcd < rr ? xcd * (qq + 1) : rr * (qq + 1) + (xcd - rr) * qq) + idx;
    const int mtile = wg / NT;
    const int ntile = wg % NT;
    const long a_row0 = (long)mtile * 128;
    const long n0     = (long)ntile * 128;

    const int slot = lane & 7;
    const __bf16* aP[4];
    const __bf16* bP[4];
#pragma unroll
    for (int it = 0; it < 4; ++it) {
        const int lrow = it * 32 + w * 8 + (lane >> 3);
        const int scol = (slot ^ (lrow & 7)) * 8;
        aP[it] = A + (a_row0 + lrow) * DM + scol;
        const int gcol = (lrow & 64) | ((lrow & 15) << 2) | ((lrow >> 4) & 3);
        bP[it] = Bw + (n0 + gcol) * DM + scol;
    }

    const f32x4 fzero = {0.f, 0.f, 0.f, 0.f};
    f32x4 acc[4][4];
#pragma unroll
    for (int i = 0; i < 4; ++i)
#pragma unroll
        for (int j = 0; j < 4; ++j) acc[i][j] = fzero;

#define STAGE(P, K0) do { \
    _Pragma("unroll") for (int it = 0; it < 4; ++it) { \
        gload_lds16(aP[it] + (K0), (char*)(&As[P][0]) + it * 4096 + w * 1024); \
        gload_lds16(bP[it] + (K0), (char*)(&Bs[P][0]) + it * 4096 + w * 1024); \
    } } while (0)

    STAGE(0, 0);
    __syncthreads();

    int cur = 0;
    for (int k0 = 0; k0 < DM; k0 += 64) {
        if (k0 + 64 < DM) STAGE(cur ^ 1, k0 + 64);

        const __bf16* pA = &As[cur][0];
        const __bf16* pB = &Bs[cur][0];
        bf16x8 af[4][2], bfr[4][2];
#pragma unroll
        for (int i = 0; i < 4; ++i) {
            const int fr = wm * 64 + i * 16 + qi;
#pragma unroll
            for (int ks = 0; ks < 2; ++ks)
                af[i][ks] = *(const bf16x8*)(pA + fr * 64 + (((ks << 2) + g) ^ (fr & 7)) * 8);
        }
#pragma unroll
        for (int j = 0; j < 4; ++j) {
            const int frb = wn * 64 + j * 16 + qi;
#pragma unroll
            for (int ks = 0; ks < 2; ++ks)
                bfr[j][ks] = *(const bf16x8*)(pB + frb * 64 + (((ks << 2) + g) ^ (frb & 7)) * 8);
        }
#pragma unroll
        for (int ks = 0; ks < 2; ++ks)
#pragma unroll
            for (int j = 0; j < 4; ++j)
#pragma unroll
                for (int i = 0; i < 4; ++i)
                    acc[i][j] = __builtin_amdgcn_mfma_f32_16x16x32_bf16(
                        af[i][ks], bfr[j][ks], acc[i][j], 0, 0, 0);

        __syncthreads();
        cur ^= 1;
    }
#undef STAGE

    const long ge0 = n0 + wn * 64 + qi * 4;
    const float4 b4 = *(const float4*)(bias + ge0);
    const float mul = (EPI == 0 && (n0 + wn * 64) < DM) ? 0.125f * 1.44269504f : 1.f;
#pragma unroll
    for (int i = 0; i < 4; ++i) {
#pragma unroll
        for (int r = 0; r < 4; ++r) {
            const long m = a_row0 + wm * 64 + i * 16 + g * 4 + r;
            if (m < MTOT) {
                if (EPI == 0) {
                    bf16x4 pv;
                    pv[0] = (__bf16)((acc[i][0][r] + b4.x) * mul);
                    pv[1] = (__bf16)((acc[i][1][r] + b4.y) * mul);
                    pv[2] = (__bf16)((acc[i][2][r] + b4.z) * mul);
                    pv[3] = (__bf16)((acc[i][3][r] + b4.w) * mul);
                    *(bf16x4*)(obf + m * EN + ge0) = pv;
                } else {
                    float4 o;
                    o.x = acc[i][0][r] + b4.x;
                    o.y = acc[i][1][r] + b4.y;
                    o.z = acc[i][2][r] + b4.z;
                    o.w = acc[i][3][r] + b4.w;
                    *(float4*)(of32 + m * EN + ge0) = o;
                }
            }
        }
    }
}

// ---------------- attention: streaming (online, no-max) softmax ----------------
// qkv layout: [M, 2304]; q = cols 0..767 (pre-scaled by 0.125*log2e), k = +768, v = +1536.
// One block per (b,h); 8 waves; waves process q-groups gi = w, w+8, w+16.
// Per j-tile (32 k's): QK MFMA -> mask+exp2 -> pack bf16 -> PV MFMA; only
// oacc/sum persist => ~90 VGPRs instead of st[22]'s ~150.
template <int NJ>
__device__ __forceinline__ void attn_group(
    const __bf16* __restrict__ qkv, const char* vL, __bf16* __restrict__ ao,
    long rowb, int h, int q0, int qi, int g)
{
    int qrow = q0 + qi; if (qrow > NTOK - 1) qrow = NTOK - 1;
    const __bf16* qsrc = qkv + (rowb + qrow) * EQKV + h * HD + g * 8;
    const bf16x8 qf0 = *(const bf16x8*)(qsrc);
    const bf16x8 qf1 = *(const bf16x8*)(qsrc + 32);

    const int qg = q0 + qi;
    int limit;
    if (qg == 0)       limit = NTOK;
    else if (qg < 5)   limit = 5;
    else if (qg < 21)  limit = 21;
    else if (qg < 85)  limit = 85;
    else               limit = NTOK;

    const f32x4 fzero = {0.f, 0.f, 0.f, 0.f};
    f32x4 oacc[4] = {fzero, fzero, fzero, fzero};
    float sum = 0.f;

    const __bf16* kbase = qkv + rowb * EQKV + DM + h * HD + g * 8;
    const int xd = (qi & 7) ^ ((qi >> 3) & 7);   // db-dependent part added per db below

#pragma unroll 2
    for (int j = 0; j < NJ; ++j) {
        // ---- QK^T for kf = 2j, 2j+1 (A-rows = k rows, loaded by qi; out k = 32j+16*hi+g*4+r)
        const int kr0 = 32 * j + qi;
        int kr1 = kr0 + 16; if (kr1 > NTOK - 1) kr1 = NTOK - 1;   // only j=10 tail clamps
        const __bf16* k0p = kbase + (long)kr0 * EQKV;
        const __bf16* k1p = kbase + (long)kr1 * EQKV;
        const bf16x8 k00 = *(const bf16x8*)(k0p);
        const bf16x8 k01 = *(const bf16x8*)(k0p + 32);
        const bf16x8 k10 = *(const bf16x8*)(k1p);
        const bf16x8 k11 = *(const bf16x8*)(k1p + 32);

        f32x4 s0 = __builtin_amdgcn_mfma_f32_16x16x32_bf16(k00, qf0, fzero, 0, 0, 0);
        s0 = __builtin_amdgcn_mfma_f32_16x16x32_bf16(k01, qf1, s0, 0, 0, 0);
        f32x4 s1 = __builtin_amdgcn_mfma_f32_16x16x32_bf16(k10, qf0, fzero, 0, 0, 0);
        s1 = __builtin_amdgcn_mfma_f32_16x16x32_bf16(k11, qf1, s1, 0, 0, 0);

        // ---- mask + exp2 + pack
        bf16x8 pf;
#pragma unroll
        for (int r = 0; r < 4; ++r) {
            const int k0i = 32 * j + g * 4 + r;
            const float p0 = (k0i < limit) ? EXP2F(s0[r]) : 0.f;
            sum += p0; pf[r] = (__bf16)p0;
            const int k1i = k0i + 16;
            const float p1 = (k1i < limit) ? EXP2F(s1[r]) : 0.f;
            sum += p1; pf[4 + r] = (__bf16)p1;
        }

        // ---- PV
#pragma unroll
        for (int db = 0; db < 4; ++db) {
            const int d  = db * 16 + qi;
            const int sp = (4 * j + g) ^ xd ^ ((2 * db) & 7);
            const bf16x8 vf = *(const bf16x8*)(vL + d * 768 + sp * 16);
            oacc[db] = __builtin_amdgcn_mfma_f32_16x16x32_bf16(vf, pf, oacc[db], 0, 0, 0);
        }
    }

    sum += __shfl_xor(sum, 16);
    sum += __shfl_xor(sum, 32);
    const float rinv = 1.f / sum;

    if (qg < NTOK) {
        const long orow = (rowb + qg) * DM + h * HD;
#pragma unroll
        for (int db = 0; db < 4; ++db) {
            bf16x4 pv;
#pragma unroll
            for (int r = 0; r < 4; ++r) pv[r] = (__bf16)(oacc[db][r] * rinv);
            *(bf16x4*)(ao + orow + db * 16 + g * 4) = pv;
        }
    }
}

__global__ __launch_bounds__(512) void attn_kernel(
    const __bf16* __restrict__ qkv, __bf16* __restrict__ ao)
{
    const int h = blockIdx.x;   // 0..11
    const int b = blockIdx.y;   // 0..63
    const long rowb = (long)b * NTOK;

    __shared__ char vL[64 * 768];   // 48 KiB, V^T fragment-order, double-XOR swizzle

    const int tid  = threadIdx.x;
    const int lane = tid & 63;
    const int w    = tid >> 6;   // 0..7

    // stage V: 352 n-rows x 8 d-chunks = 2816 pieces
#pragma unroll
    for (int it = 0; it < 6; ++it) {
        const int c = it * 512 + tid;
        if (c < 2816) {
            const int n  = c >> 3;
            const int dc = (c & 7) << 3;
            bf16x8 e;
            if (n < NTOK) e = *(const bf16x8*)(qkv + (rowb + n) * EQKV + 1536 + h * HD + dc);
            else { e[0]=e[1]=e[2]=e[3]=e[4]=e[5]=e[6]=e[7] = (__bf16)0.f; }
            const int s   = ((n >> 5) << 2) | ((n >> 2) & 3);     // 4j+g
            const int off = (((n >> 4) & 1) << 3) | ((n & 3) << 1);
            const int x   = c & 7;                                 // (d>>3)&7
#pragma unroll
            for (int i = 0; i < 8; ++i) {
                const int sp = s ^ i ^ x;                          // i == d&7
                *(__bf16*)(vL + (dc + i) * 768 + sp * 16 + off) = e[i];
            }
        }
    }
    __syncthreads();

    const int g  = lane >> 4;
    const int qi = lane & 15;

    // each wave: q-groups gi = w, w+8, w+16 (22 groups total)
    for (int gi = w; gi < 22; gi += 8) {
        const int q0 = gi * 16;
        if (gi >= 1 && gi <= 4)
            attn_group<3>(qkv, vL, ao, rowb, h, q0, qi, g);
        else
            attn_group<11>(qkv, vL, ao, rowb, h, q0, qi, g);
    }
}

extern "C" void kernel_launch(void* const* d_in, const int* in_sizes, int n_in,
                              void* d_out, int out_size, void* d_ws, size_t ws_size,
                              hipStream_t stream) {
    const float* x      = (const float*)d_in[0];
    const float* qkv_w  = (const float*)d_in[1];
    const float* qkv_b  = (const float*)d_in[2];
    const float* proj_w = (const float*)d_in[3];
    const float* proj_b = (const float*)d_in[4];
    float* out = (float*)d_out;

    char* ws = (char*)d_ws;
    constexpr size_t XB_BYTES  = (size_t)MP * DM * 2;
    constexpr size_t WQ_OFF    = XB_BYTES;
    constexpr size_t WP_OFF    = WQ_OFF + (size_t)EQKV * DM * 2;
    constexpr size_t QKV_OFF   = WP_OFF + (size_t)DM * DM * 2;

    __bf16* xb  = (__bf16*)(ws);           // x bf16 [MP,768]; reused as attn-out
    __bf16* wq  = (__bf16*)(ws + WQ_OFF);
    __bf16* wp  = (__bf16*)(ws + WP_OFF);
    __bf16* qkv = (__bf16*)(ws + QKV_OFF); // [MTOT, 2304] bf16

    cvt_kernel<<<2048, 256, 0, stream>>>(x,      xb, MTOT * DM / 4);
    cvt_kernel<<<1728, 256, 0, stream>>>(qkv_w,  wq, EQKV * DM / 4);
    cvt_kernel<<<576,  256, 0, stream>>>(proj_w, wp, DM * DM / 4);

    gemm128<0, EQKV, 18><<<171 * 18, 256, 0, stream>>>(xb, wq, qkv_b, qkv, nullptr);
    attn_kernel<<<dim3(NH, B_SZ), 512, 0, stream>>>(qkv, xb);
    gemm128<1, DM, 6><<<171 * 6, 256, 0, stream>>>(xb, wp, proj_b, nullptr, out);
}